// Round 3
// baseline (469.521 us; speedup 1.0000x reference)
//
#include <hip/hip_runtime.h>

// GraphConvolution: out = A_coo @ (x @ W)
// x: [100000, 256] f32, W: [256, 64] f32, A: 1.6M edges (rows, cols int32, vals f32)
//
// Phase 1: support = x @ W   (fp32 vector GEMM; no fp32 MFMA on CDNA4)
// Phase 2: CSR build (hist + scan + bucket) then per-row gather-reduce.
//          102.4M fp32 atomics (naive) -> 3.2M int atomics + streaming.
// Fallback: if ws too small for CSR buffers, atomic-scatter path.

#define KDIM 256
#define MDIM 64

// ---------------------------------------------------------------- GEMM
// Block tile 128 rows x 64 feats, K-tile 64. Thread tile 8 rows x 4 feats.
// LDS: xs swizzled (q' = q ^ ((row>>3)&3)) so the 4-row b128 read set hits
// distinct bank quads; ws2 kk-major so the 4-feat read is one b128.
__global__ __launch_bounds__(256) void gemm_xw(
    const float* __restrict__ x, const float* __restrict__ W,
    float* __restrict__ support, int nrows)
{
    __shared__ float xs[128][64];   // 32 KB, col-group XOR swizzle
    __shared__ float ws2[64][64];   // 16 KB, ws2[kk][f]
    const int tid = threadIdx.x;
    const int tr  = tid >> 4;        // 0..15 row-group
    const int f0  = (tid & 15) * 4;  // feature base
    const int swz = tr & 3;          // xs read swizzle key ((row>>3)&3, row=tr*8+i)
    const int row0 = blockIdx.x * 128;

    float acc[8][4];
    #pragma unroll
    for (int i = 0; i < 8; ++i)
        #pragma unroll
        for (int j = 0; j < 4; ++j) acc[i][j] = 0.f;

    for (int kt = 0; kt < KDIM; kt += 64) {
        __syncthreads();
        // stage x tile: 128 rows x 16 float4-slots
        #pragma unroll
        for (int i = 0; i < 8; ++i) {
            int slot = tid + i * 256;
            int r = slot >> 4;
            int q = slot & 15;
            int grow = row0 + r;
            float4 v = make_float4(0.f, 0.f, 0.f, 0.f);
            if (grow < nrows)
                v = *reinterpret_cast<const float4*>(
                        &x[(size_t)grow * KDIM + kt + q * 4]);
            int qs = q ^ ((r >> 3) & 3);
            *reinterpret_cast<float4*>(&xs[r][qs * 4]) = v;
        }
        // stage W tile kk-major: 64 kk x 16 float4-slots (no transpose needed)
        #pragma unroll
        for (int i = 0; i < 4; ++i) {
            int slot = tid + i * 256;
            int kk = slot >> 4;
            int q = slot & 15;
            float4 v = *reinterpret_cast<const float4*>(
                           &W[(size_t)(kt + kk) * MDIM + q * 4]);
            *reinterpret_cast<float4*>(&ws2[kk][q * 4]) = v;
        }
        __syncthreads();

        #pragma unroll 2
        for (int kk = 0; kk < 64; kk += 4) {
            const int q4 = kk >> 2;
            float4 xv[8];
            #pragma unroll
            for (int i = 0; i < 8; ++i)
                xv[i] = *reinterpret_cast<const float4*>(
                            &xs[tr * 8 + i][(q4 ^ swz) * 4]);
            #pragma unroll
            for (int k2 = 0; k2 < 4; ++k2) {
                float4 wv = *reinterpret_cast<const float4*>(&ws2[kk + k2][f0]);
                #pragma unroll
                for (int i = 0; i < 8; ++i) {
                    const float xk = (k2 == 0) ? xv[i].x :
                                     (k2 == 1) ? xv[i].y :
                                     (k2 == 2) ? xv[i].z : xv[i].w;
                    acc[i][0] = fmaf(xk, wv.x, acc[i][0]);
                    acc[i][1] = fmaf(xk, wv.y, acc[i][1]);
                    acc[i][2] = fmaf(xk, wv.z, acc[i][2]);
                    acc[i][3] = fmaf(xk, wv.w, acc[i][3]);
                }
            }
        }
    }

    #pragma unroll
    for (int i = 0; i < 8; ++i) {
        int grow = row0 + tr * 8 + i;
        if (grow < nrows) {
            float4 v = make_float4(acc[i][0], acc[i][1], acc[i][2], acc[i][3]);
            *reinterpret_cast<float4*>(&support[(size_t)grow * MDIM + f0]) = v;
        }
    }
}

// ------------------------------------------------------------ CSR build
__global__ __launch_bounds__(256) void hist_rows(
    const int* __restrict__ rows, int* __restrict__ counts, int nedges)
{
    int e = blockIdx.x * 256 + threadIdx.x;
    const int stride = gridDim.x * 256;
    for (; e < nedges; e += stride)
        atomicAdd(&counts[rows[e]], 1);
}

// Block scans 1024 counts (4/thread); exclusive offsets; block total -> partials.
__global__ __launch_bounds__(256) void scan_blocks(
    const int* __restrict__ counts, int* __restrict__ offsets,
    int* __restrict__ partials, int n)
{
    __shared__ int sh[256];
    const int t = threadIdx.x;
    const int base = blockIdx.x * 1024 + t * 4;
    int v0 = 0, v1 = 0, v2 = 0, v3 = 0;
    if (base + 3 < n) {
        int4 vv = *reinterpret_cast<const int4*>(&counts[base]);
        v0 = vv.x; v1 = vv.y; v2 = vv.z; v3 = vv.w;
    } else {
        if (base + 0 < n) v0 = counts[base + 0];
        if (base + 1 < n) v1 = counts[base + 1];
        if (base + 2 < n) v2 = counts[base + 2];
    }
    const int tsum = v0 + v1 + v2 + v3;
    sh[t] = tsum;
    __syncthreads();
    for (int off = 1; off < 256; off <<= 1) {
        int xv = (t >= off) ? sh[t - off] : 0;
        __syncthreads();
        sh[t] += xv;
        __syncthreads();
    }
    int excl = sh[t] - tsum;
    if (t == 255) partials[blockIdx.x] = sh[255];
    if (base + 0 < n) offsets[base + 0] = excl;  excl += v0;
    if (base + 1 < n) offsets[base + 1] = excl;  excl += v1;
    if (base + 2 < n) offsets[base + 2] = excl;  excl += v2;
    if (base + 3 < n) offsets[base + 3] = excl;
}

// Parallel exclusive scan of block partials (nb <= 256).
__global__ __launch_bounds__(256) void scan_partials(int* partials, int nb)
{
    __shared__ int sh[256];
    const int t = threadIdx.x;
    const int v = (t < nb) ? partials[t] : 0;
    sh[t] = v;
    __syncthreads();
    for (int off = 1; off < 256; off <<= 1) {
        int xv = (t >= off) ? sh[t - off] : 0;
        __syncthreads();
        sh[t] += xv;
        __syncthreads();
    }
    if (t < nb) partials[t] = sh[t] - v;
}

// offsets += block partial; also seed cursor = offsets (bucket atomics run on it)
__global__ __launch_bounds__(256) void scan_addback(
    int* __restrict__ offsets, int* __restrict__ cursor,
    const int* __restrict__ partials, int n)
{
    int i = blockIdx.x * 256 + threadIdx.x;
    if (i < n) {
        int o = offsets[i] + partials[i >> 10];
        offsets[i] = o;
        cursor[i] = o;
    }
}

__global__ __launch_bounds__(256) void bucket_edges(
    const int* __restrict__ rows, const int* __restrict__ cols,
    const float* __restrict__ vals, int* __restrict__ cursor,
    int* __restrict__ ecol, float* __restrict__ eval, int nedges)
{
    int e = blockIdx.x * 256 + threadIdx.x;
    const int stride = gridDim.x * 256;
    for (; e < nedges; e += stride) {
        const int pos = atomicAdd(&cursor[rows[e]], 1);
        ecol[pos] = cols[e];
        eval[pos] = vals[e];
    }
}

// ---------------------------------------------------------- SpMM reduce
// One 16-lane group per row; lane owns 4 features (float4 gather from
// L2/L3-resident support). out written exactly once -> no atomics/memset.
__global__ __launch_bounds__(256) void spmm_reduce(
    const int* __restrict__ offsets, const int* __restrict__ counts,
    const int* __restrict__ ecol, const float* __restrict__ eval,
    const float* __restrict__ support, float* __restrict__ out, int nrows)
{
    const int g = blockIdx.x * 16 + (threadIdx.x >> 4);
    const int f0 = (threadIdx.x & 15) * 4;
    if (g >= nrows) return;
    const int beg = offsets[g];
    const int end = beg + counts[g];
    float ax = 0.f, ay = 0.f, az = 0.f, aw = 0.f;
    for (int e = beg; e < end; ++e) {
        const int c = ecol[e];
        const float v = eval[e];
        float4 s = *reinterpret_cast<const float4*>(
                       &support[(size_t)c * MDIM + f0]);
        ax = fmaf(v, s.x, ax);
        ay = fmaf(v, s.y, ay);
        az = fmaf(v, s.z, az);
        aw = fmaf(v, s.w, aw);
    }
    *reinterpret_cast<float4*>(&out[(size_t)g * MDIM + f0]) =
        make_float4(ax, ay, az, aw);
}

// ----------------------------------------------- fallback atomic scatter
__global__ __launch_bounds__(256) void scatter_edges(
    const int* __restrict__ rows, const int* __restrict__ cols,
    const float* __restrict__ vals, const float* __restrict__ support,
    float* __restrict__ out, int nedges)
{
    const int t = blockIdx.x * blockDim.x + threadIdx.x;
    const int fq = (t & 15) * 4;
    int e = t >> 4;
    const int estride = (gridDim.x * blockDim.x) >> 4;
    for (; e < nedges; e += estride) {
        const int r = rows[e];
        const int c = cols[e];
        const float v = vals[e];
        float4 s = *reinterpret_cast<const float4*>(
                       &support[(size_t)c * MDIM + fq]);
        float* op = &out[(size_t)r * MDIM + fq];
        atomicAdd(op + 0, v * s.x);
        atomicAdd(op + 1, v * s.y);
        atomicAdd(op + 2, v * s.z);
        atomicAdd(op + 3, v * s.w);
    }
}

// ---------------------------------------------------------------- launch
extern "C" void kernel_launch(void* const* d_in, const int* in_sizes, int n_in,
                              void* d_out, int out_size, void* d_ws, size_t ws_size,
                              hipStream_t stream) {
    const float* x    = (const float*)d_in[0];
    const int*   rows = (const int*)d_in[1];
    const int*   cols = (const int*)d_in[2];
    const float* vals = (const float*)d_in[3];
    const float* W    = (const float*)d_in[4];
    float* out = (float*)d_out;

    const int nnodes = in_sizes[0] / KDIM;   // 100000
    const int nedges = in_sizes[1];          // 1600000

    auto align256 = [](size_t v) { return (v + 255) & ~(size_t)255; };
    const size_t sz_support = align256((size_t)nnodes * MDIM * 4);
    const size_t sz_nodes   = align256((size_t)nnodes * 4);
    const size_t sz_part    = align256(1024 * 4);
    const size_t sz_edges   = align256((size_t)nedges * 4);
    const size_t need = sz_support + 3 * sz_nodes + sz_part + 2 * sz_edges;

    char* w = (char*)d_ws;
    float* support = (float*)w;  w += sz_support;

    gemm_xw<<<dim3((nnodes + 127) / 128), dim3(256), 0, stream>>>(
        x, W, support, nnodes);

    if (ws_size >= need) {
        int* counts   = (int*)w;   w += sz_nodes;
        int* offsets  = (int*)w;   w += sz_nodes;
        int* cursor   = (int*)w;   w += sz_nodes;
        int* partials = (int*)w;   w += sz_part;
        int* ecol     = (int*)w;   w += sz_edges;
        float* eval   = (float*)w;

        const int nb = (nnodes + 1023) / 1024;   // 98 (<=256 for scan_partials)

        hipMemsetAsync(counts, 0, (size_t)nnodes * 4, stream);

        hist_rows<<<dim3(2048), dim3(256), 0, stream>>>(rows, counts, nedges);
        scan_blocks<<<dim3(nb), dim3(256), 0, stream>>>(
            counts, offsets, partials, nnodes);
        scan_partials<<<dim3(1), dim3(256), 0, stream>>>(partials, nb);
        scan_addback<<<dim3((nnodes + 255) / 256), dim3(256), 0, stream>>>(
            offsets, cursor, partials, nnodes);
        bucket_edges<<<dim3(4096), dim3(256), 0, stream>>>(
            rows, cols, vals, cursor, ecol, eval, nedges);
        spmm_reduce<<<dim3((nnodes + 15) / 16), dim3(256), 0, stream>>>(
            offsets, counts, ecol, eval, support, out, nnodes);
    } else {
        // Workspace too small for CSR buffers: atomic-scatter fallback.
        hipMemsetAsync(d_out, 0, (size_t)out_size * sizeof(float), stream);
        scatter_edges<<<dim3(4096), dim3(256), 0, stream>>>(
            rows, cols, vals, support, out, nedges);
    }
}

// Round 4
// 466.175 us; speedup vs baseline: 1.0072x; 1.0072x over previous
//
#include <hip/hip_runtime.h>

// GraphConvolution: out = A_coo @ (x @ W)
// x: [100000, 256] f32, W: [256, 64] f32, A: 1.6M edges (rows, cols int32, vals f32)
//
// Phase 1: support = x @ W   (fp32 vector GEMM; no fp32 MFMA on CDNA4)
// Phase 2: CSR build (hist + scan + bucket) then per-row gather-reduce.
// R3 -> R4: bucket scatter now writes ONE 8B {col,val} pair instead of two
//           4B stores to separate arrays (measured 12x write amplification,
//           WRITE_SIZE 153.7MB for 12.8MB payload). spmm loop unrolled x4
//           for memory-level parallelism on the L3-resident support gathers.

#define KDIM 256
#define MDIM 64

// ---------------------------------------------------------------- GEMM
// Block tile 128 rows x 64 feats, K-tile 64. Thread tile 8 rows x 4 feats.
// xs staged with col-group XOR swizzle so the 4-row b128 read set in a wave
// hits distinct bank quads; ws2 kk-major so the 4-feat read is one b128.
__global__ __launch_bounds__(256) void gemm_xw(
    const float* __restrict__ x, const float* __restrict__ W,
    float* __restrict__ support, int nrows)
{
    __shared__ float xs[128][64];   // 32 KB
    __shared__ float ws2[64][64];   // 16 KB
    const int tid = threadIdx.x;
    const int tr  = tid >> 4;        // 0..15 row-group
    const int f0  = (tid & 15) * 4;  // feature base
    const int swz = tr & 3;
    const int row0 = blockIdx.x * 128;

    float acc[8][4];
    #pragma unroll
    for (int i = 0; i < 8; ++i)
        #pragma unroll
        for (int j = 0; j < 4; ++j) acc[i][j] = 0.f;

    for (int kt = 0; kt < KDIM; kt += 64) {
        __syncthreads();
        #pragma unroll
        for (int i = 0; i < 8; ++i) {
            int slot = tid + i * 256;
            int r = slot >> 4;
            int q = slot & 15;
            int grow = row0 + r;
            float4 v = make_float4(0.f, 0.f, 0.f, 0.f);
            if (grow < nrows)
                v = *reinterpret_cast<const float4*>(
                        &x[(size_t)grow * KDIM + kt + q * 4]);
            int qs = q ^ ((r >> 3) & 3);
            *reinterpret_cast<float4*>(&xs[r][qs * 4]) = v;
        }
        #pragma unroll
        for (int i = 0; i < 4; ++i) {
            int slot = tid + i * 256;
            int kk = slot >> 4;
            int q = slot & 15;
            float4 v = *reinterpret_cast<const float4*>(
                           &W[(size_t)(kt + kk) * MDIM + q * 4]);
            *reinterpret_cast<float4*>(&ws2[kk][q * 4]) = v;
        }
        __syncthreads();

        #pragma unroll 2
        for (int kk = 0; kk < 64; kk += 4) {
            const int q4 = kk >> 2;
            float4 xv[8];
            #pragma unroll
            for (int i = 0; i < 8; ++i)
                xv[i] = *reinterpret_cast<const float4*>(
                            &xs[tr * 8 + i][(q4 ^ swz) * 4]);
            #pragma unroll
            for (int k2 = 0; k2 < 4; ++k2) {
                float4 wv = *reinterpret_cast<const float4*>(&ws2[kk + k2][f0]);
                #pragma unroll
                for (int i = 0; i < 8; ++i) {
                    const float xk = (k2 == 0) ? xv[i].x :
                                     (k2 == 1) ? xv[i].y :
                                     (k2 == 2) ? xv[i].z : xv[i].w;
                    acc[i][0] = fmaf(xk, wv.x, acc[i][0]);
                    acc[i][1] = fmaf(xk, wv.y, acc[i][1]);
                    acc[i][2] = fmaf(xk, wv.z, acc[i][2]);
                    acc[i][3] = fmaf(xk, wv.w, acc[i][3]);
                }
            }
        }
    }

    #pragma unroll
    for (int i = 0; i < 8; ++i) {
        int grow = row0 + tr * 8 + i;
        if (grow < nrows) {
            float4 v = make_float4(acc[i][0], acc[i][1], acc[i][2], acc[i][3]);
            *reinterpret_cast<float4*>(&support[(size_t)grow * MDIM + f0]) = v;
        }
    }
}

// ------------------------------------------------------------ CSR build
__global__ __launch_bounds__(256) void hist_rows(
    const int* __restrict__ rows, int* __restrict__ counts, int nedges)
{
    int e = blockIdx.x * 256 + threadIdx.x;
    const int stride = gridDim.x * 256;
    for (; e < nedges; e += stride)
        atomicAdd(&counts[rows[e]], 1);
}

// Block scans 1024 counts (4/thread); exclusive offsets; block total -> partials.
__global__ __launch_bounds__(256) void scan_blocks(
    const int* __restrict__ counts, int* __restrict__ offsets,
    int* __restrict__ partials, int n)
{
    __shared__ int sh[256];
    const int t = threadIdx.x;
    const int base = blockIdx.x * 1024 + t * 4;
    int v0 = 0, v1 = 0, v2 = 0, v3 = 0;
    if (base + 3 < n) {
        int4 vv = *reinterpret_cast<const int4*>(&counts[base]);
        v0 = vv.x; v1 = vv.y; v2 = vv.z; v3 = vv.w;
    } else {
        if (base + 0 < n) v0 = counts[base + 0];
        if (base + 1 < n) v1 = counts[base + 1];
        if (base + 2 < n) v2 = counts[base + 2];
    }
    const int tsum = v0 + v1 + v2 + v3;
    sh[t] = tsum;
    __syncthreads();
    for (int off = 1; off < 256; off <<= 1) {
        int xv = (t >= off) ? sh[t - off] : 0;
        __syncthreads();
        sh[t] += xv;
        __syncthreads();
    }
    int excl = sh[t] - tsum;
    if (t == 255) partials[blockIdx.x] = sh[255];
    if (base + 0 < n) offsets[base + 0] = excl;  excl += v0;
    if (base + 1 < n) offsets[base + 1] = excl;  excl += v1;
    if (base + 2 < n) offsets[base + 2] = excl;  excl += v2;
    if (base + 3 < n) offsets[base + 3] = excl;
}

// Parallel exclusive scan of block partials (nb <= 256).
__global__ __launch_bounds__(256) void scan_partials(int* partials, int nb)
{
    __shared__ int sh[256];
    const int t = threadIdx.x;
    const int v = (t < nb) ? partials[t] : 0;
    sh[t] = v;
    __syncthreads();
    for (int off = 1; off < 256; off <<= 1) {
        int xv = (t >= off) ? sh[t - off] : 0;
        __syncthreads();
        sh[t] += xv;
        __syncthreads();
    }
    if (t < nb) partials[t] = sh[t] - v;
}

// offsets += block partial; also seed cursor = offsets.
__global__ __launch_bounds__(256) void scan_addback(
    int* __restrict__ offsets, int* __restrict__ cursor,
    const int* __restrict__ partials, int n)
{
    int i = blockIdx.x * 256 + threadIdx.x;
    if (i < n) {
        int o = offsets[i] + partials[i >> 10];
        offsets[i] = o;
        cursor[i] = o;
    }
}

// One 8B scattered store per edge ({col, val_bits} pair) instead of two 4B
// stores to separate arrays: halves dirty-line footprint.
__global__ __launch_bounds__(256) void bucket_edges(
    const int* __restrict__ rows, const int* __restrict__ cols,
    const float* __restrict__ vals, int* __restrict__ cursor,
    int2* __restrict__ edata, int nedges)
{
    int e = blockIdx.x * 256 + threadIdx.x;
    const int stride = gridDim.x * 256;
    for (; e < nedges; e += stride) {
        const int pos = atomicAdd(&cursor[rows[e]], 1);
        int2 pk;
        pk.x = cols[e];
        pk.y = __float_as_int(vals[e]);
        edata[pos] = pk;
    }
}

// ---------------------------------------------------------- SpMM reduce
// One 16-lane group per row; lane owns 4 features. Edge loop unrolled x4:
// 4 independent support gathers in flight per iteration (MLP).
__global__ __launch_bounds__(256) void spmm_reduce(
    const int* __restrict__ offsets, const int* __restrict__ counts,
    const int2* __restrict__ edata, const float* __restrict__ support,
    float* __restrict__ out, int nrows)
{
    const int g = blockIdx.x * 16 + (threadIdx.x >> 4);
    const int f0 = (threadIdx.x & 15) * 4;
    if (g >= nrows) return;
    int e = offsets[g];
    const int end = e + counts[g];
    float ax = 0.f, ay = 0.f, az = 0.f, aw = 0.f;

    for (; e + 4 <= end; e += 4) {
        const int2 p0 = edata[e + 0];
        const int2 p1 = edata[e + 1];
        const int2 p2 = edata[e + 2];
        const int2 p3 = edata[e + 3];
        float4 s0 = *reinterpret_cast<const float4*>(
                        &support[(size_t)p0.x * MDIM + f0]);
        float4 s1 = *reinterpret_cast<const float4*>(
                        &support[(size_t)p1.x * MDIM + f0]);
        float4 s2 = *reinterpret_cast<const float4*>(
                        &support[(size_t)p2.x * MDIM + f0]);
        float4 s3 = *reinterpret_cast<const float4*>(
                        &support[(size_t)p3.x * MDIM + f0]);
        const float v0 = __int_as_float(p0.y);
        const float v1 = __int_as_float(p1.y);
        const float v2 = __int_as_float(p2.y);
        const float v3 = __int_as_float(p3.y);
        ax = fmaf(v0, s0.x, ax); ay = fmaf(v0, s0.y, ay);
        az = fmaf(v0, s0.z, az); aw = fmaf(v0, s0.w, aw);
        ax = fmaf(v1, s1.x, ax); ay = fmaf(v1, s1.y, ay);
        az = fmaf(v1, s1.z, az); aw = fmaf(v1, s1.w, aw);
        ax = fmaf(v2, s2.x, ax); ay = fmaf(v2, s2.y, ay);
        az = fmaf(v2, s2.z, az); aw = fmaf(v2, s2.w, aw);
        ax = fmaf(v3, s3.x, ax); ay = fmaf(v3, s3.y, ay);
        az = fmaf(v3, s3.z, az); aw = fmaf(v3, s3.w, aw);
    }
    for (; e < end; ++e) {
        const int2 p = edata[e];
        const float v = __int_as_float(p.y);
        float4 s = *reinterpret_cast<const float4*>(
                       &support[(size_t)p.x * MDIM + f0]);
        ax = fmaf(v, s.x, ax); ay = fmaf(v, s.y, ay);
        az = fmaf(v, s.z, az); aw = fmaf(v, s.w, aw);
    }
    *reinterpret_cast<float4*>(&out[(size_t)g * MDIM + f0]) =
        make_float4(ax, ay, az, aw);
}

// ----------------------------------------------- fallback atomic scatter
__global__ __launch_bounds__(256) void scatter_edges(
    const int* __restrict__ rows, const int* __restrict__ cols,
    const float* __restrict__ vals, const float* __restrict__ support,
    float* __restrict__ out, int nedges)
{
    const int t = blockIdx.x * blockDim.x + threadIdx.x;
    const int fq = (t & 15) * 4;
    int e = t >> 4;
    const int estride = (gridDim.x * blockDim.x) >> 4;
    for (; e < nedges; e += estride) {
        const int r = rows[e];
        const int c = cols[e];
        const float v = vals[e];
        float4 s = *reinterpret_cast<const float4*>(
                       &support[(size_t)c * MDIM + fq]);
        float* op = &out[(size_t)r * MDIM + fq];
        atomicAdd(op + 0, v * s.x);
        atomicAdd(op + 1, v * s.y);
        atomicAdd(op + 2, v * s.z);
        atomicAdd(op + 3, v * s.w);
    }
}

// ---------------------------------------------------------------- launch
extern "C" void kernel_launch(void* const* d_in, const int* in_sizes, int n_in,
                              void* d_out, int out_size, void* d_ws, size_t ws_size,
                              hipStream_t stream) {
    const float* x    = (const float*)d_in[0];
    const int*   rows = (const int*)d_in[1];
    const int*   cols = (const int*)d_in[2];
    const float* vals = (const float*)d_in[3];
    const float* W    = (const float*)d_in[4];
    float* out = (float*)d_out;

    const int nnodes = in_sizes[0] / KDIM;   // 100000
    const int nedges = in_sizes[1];          // 1600000

    auto align256 = [](size_t v) { return (v + 255) & ~(size_t)255; };
    const size_t sz_support = align256((size_t)nnodes * MDIM * 4);
    const size_t sz_nodes   = align256((size_t)nnodes * 4);
    const size_t sz_part    = align256(1024 * 4);
    const size_t sz_edata   = align256((size_t)nedges * 8);
    const size_t need = sz_support + 3 * sz_nodes + sz_part + sz_edata;

    char* w = (char*)d_ws;
    float* support = (float*)w;  w += sz_support;

    gemm_xw<<<dim3((nnodes + 127) / 128), dim3(256), 0, stream>>>(
        x, W, support, nnodes);

    if (ws_size >= need) {
        int* counts   = (int*)w;   w += sz_nodes;
        int* offsets  = (int*)w;   w += sz_nodes;
        int* cursor   = (int*)w;   w += sz_nodes;
        int* partials = (int*)w;   w += sz_part;
        int2* edata   = (int2*)w;

        const int nb = (nnodes + 1023) / 1024;   // 98 (<=256)

        hipMemsetAsync(counts, 0, (size_t)nnodes * 4, stream);

        hist_rows<<<dim3(2048), dim3(256), 0, stream>>>(rows, counts, nedges);
        scan_blocks<<<dim3(nb), dim3(256), 0, stream>>>(
            counts, offsets, partials, nnodes);
        scan_partials<<<dim3(1), dim3(256), 0, stream>>>(partials, nb);
        scan_addback<<<dim3((nnodes + 255) / 256), dim3(256), 0, stream>>>(
            offsets, cursor, partials, nnodes);
        bucket_edges<<<dim3(4096), dim3(256), 0, stream>>>(
            rows, cols, vals, cursor, edata, nedges);
        spmm_reduce<<<dim3((nnodes + 15) / 16), dim3(256), 0, stream>>>(
            offsets, counts, edata, support, out, nnodes);
    } else {
        // Workspace too small for CSR buffers: atomic-scatter fallback.
        hipMemsetAsync(d_out, 0, (size_t)out_size * sizeof(float), stream);
        scatter_edges<<<dim3(4096), dim3(256), 0, stream>>>(
            rows, cols, vals, support, out, nedges);
    }
}